// Round 11
// baseline (303.407 us; speedup 1.0000x reference)
//
#include <hip/hip_runtime.h>
#include <hip/hip_fp16.h>

#define B_ 64
#define F_ 4
#define M_ 4096
#define D_ 1024
#define W_ 16      // u64 words per D bits
#define CW_ 64     // u64 words per M bits
#define NITER 15
#define NBLK 64    // loop blocks: f(4) x dg(16)
#define FPAD 32    // ints per flag line (128B)

typedef _Float16 f16;
typedef _Float16 f16x8 __attribute__((ext_vector_type(8)));
typedef float f32x4 __attribute__((ext_vector_type(4)));
typedef unsigned int u32;
typedef unsigned short u16;
typedef unsigned long long u64;

#define LD_AG(p)     __hip_atomic_load((p), __ATOMIC_RELAXED, __HIP_MEMORY_SCOPE_AGENT)
#define ST_AG(p, v)  __hip_atomic_store((p), (v), __ATOMIC_RELAXED, __HIP_MEMORY_SCOPE_AGENT)

// ---- device-global scratch (rebuilt every call) ----
__device__ __align__(16) u64 g_cbBits[F_ * M_ * W_];    // 2 MB: cb packed along d
__device__ __align__(16) u64 g_colBits[F_ * D_ * CW_];  // 2 MB: cb packed along m
__device__ __align__(16) f16 g_G[F_ * D_ * D_];         // 8 MB: G = cb^T cb (even ints <=4096, exact fp16)
__device__ __align__(16) u64 g_inBits[B_ * W_];
// est ping-pong, layout [w][f][b]: block (f,dg) writes [dg][f][0..63] = 512B exclusive
__device__ __align__(16) u64 g_est[2][W_ * F_ * B_];
__device__ int g_done[NITER][NBLK * FPAD];              // barrier flags, one 128B line per block
__device__ int g_mism[NITER][NBLK * FPAD];              // mismatch flags, one 128B line per block

__device__ __forceinline__ u32 nib16(u32 x) {
    x &= 0x0F0F0F0Fu;
    x = (x | (x >> 4)) & 0x00FF00FFu;
    x = (x | (x >> 8)) & 0x0000FFFFu;
    return x;
}

// ---- bit-pack via nibble-LDS + zero flag arrays ----
__global__ __launch_bounds__(256) void k_pack(const float* __restrict__ inp,
                                              const float* __restrict__ est0,
                                              const float* __restrict__ cb) {
    __shared__ unsigned char nib[4096];   // 4 waves x 4 rows x 256 nibbles
    int blk = blockIdx.x, tid = threadIdx.x;
    int wv = tid >> 6, lane = tid & 63;
    const float* src; u64* dst; int r0; int estmode = 0;
    if (blk < 1024)      { src = cb;   dst = g_cbBits; r0 = blk * 16; }
    else if (blk < 1040) { src = est0; dst = g_est[0]; r0 = (blk - 1024) * 16; estmode = 1; }
    else if (blk < 1044) { src = inp;  dst = g_inBits; r0 = (blk - 1040) * 16; }
    else {                                 // zero g_done + g_mism
        int idx = (blk - 1044) * 256 + tid;
        const int n = NITER * NBLK * FPAD;
        if (idx < n) ((int*)g_done)[idx] = 0;
        else if (idx < 2 * n) ((int*)g_mism)[idx - n] = 0;
        return;
    }
    int rw = r0 + wv * 4;
    unsigned char* mynib = nib + wv * 1024;
    #pragma unroll
    for (int rr = 0; rr < 4; rr++) {
        const float4* s4 = (const float4*)(src + (size_t)(rw + rr) * D_);
        #pragma unroll
        for (int it = 0; it < 4; it++) {
            float4 v = s4[it * 64 + lane];
            u32 n = (__float_as_uint(v.x) >> 31)
                  | (((__float_as_uint(v.y) >> 31)) << 1)
                  | (((__float_as_uint(v.z) >> 31)) << 2)
                  | (((__float_as_uint(v.w) >> 31)) << 3);
            mynib[rr * 256 + it * 64 + lane] = (unsigned char)n;
        }
    }
    uint4 q = *(const uint4*)(mynib + (lane >> 4) * 256 + (lane & 15) * 16);
    u32 w0 = nib16(q.x), w1 = nib16(q.y), w2 = nib16(q.z), w3 = nib16(q.w);
    u64 word = (u64)(w0 | (w1 << 16)) | ((u64)(w2 | (w3 << 16)) << 32);
    int r = rw + (lane >> 4), w = lane & 15;
    size_t oi = estmode ? (size_t)((w * 4 + (r & 3)) * 64 + (r >> 2))   // [w][f][b]
                        : (size_t)r * W_ + w;
    dst[oi] = word;
}

// ---- 64x64 bit-transpose: cbBits[m][wd] -> colBits[d][wm] ----
__global__ __launch_bounds__(256) void k_bitT() {
    int tid = threadIdx.x, wv = tid >> 6, lane = tid & 63;
    int tbase = (blockIdx.x * 4 + wv) * 4;
    for (int q = 0; q < 4; q++) {
        int task = tbase + q;
        int mt = task & 63;
        int wd = (task >> 6) & 15;
        int f  = task >> 10;
        u64 row = g_cbBits[((size_t)(f * M_ + mt * 64 + lane)) * W_ + wd];
        u64 myout = 0;
        #pragma unroll
        for (int j = 0; j < 64; j++) {
            u64 t = __ballot((row >> j) & 1ULL);
            if (lane == j) myout = t;
        }
        g_colBits[((size_t)(f * D_ + wd * 64 + lane)) * CW_ + mt] = myout;
    }
}

// ---- G = cb^T cb, symmetric: only t1<=t2 pairs; mirror via LDS transpose ----
__global__ __launch_bounds__(256) void k_G() {
    int blk = blockIdx.x;                  // 544 = f(4) x 136 pairs
    int f = blk / 136;
    int pi = blk % 136;
    int t1 = 0;
    while (pi >= 16 - t1) { pi -= 16 - t1; t1++; }
    int t2 = t1 + pi;
    __shared__ u64 L1T[64][64];            // [w][d_loc]
    __shared__ u64 L2T[64][64];
    int tid = threadIdx.x;
    int wv = tid >> 6, lane = tid & 63;
    for (int it = 0; it < 16; it++) {
        int w = it * 4 + wv;
        L1T[w][lane] = g_colBits[((size_t)(f * D_ + t1 * 64 + lane)) * CW_ + w];
        L2T[w][lane] = g_colBits[((size_t)(f * D_ + t2 * 64 + lane)) * CW_ + w];
    }
    __syncthreads();
    int g1 = tid >> 4, g2 = tid & 15;
    int p[4][4] = {};
    for (int w = 0; w < 64; w++) {
        u64 a0 = L1T[w][g1], a1 = L1T[w][g1 + 16], a2 = L1T[w][g1 + 32], a3 = L1T[w][g1 + 48];
        u64 b0 = L2T[w][g2], b1 = L2T[w][g2 + 16], b2 = L2T[w][g2 + 32], b3 = L2T[w][g2 + 48];
        p[0][0] += __popcll(a0 ^ b0); p[0][1] += __popcll(a0 ^ b1);
        p[0][2] += __popcll(a0 ^ b2); p[0][3] += __popcll(a0 ^ b3);
        p[1][0] += __popcll(a1 ^ b0); p[1][1] += __popcll(a1 ^ b1);
        p[1][2] += __popcll(a1 ^ b2); p[1][3] += __popcll(a1 ^ b3);
        p[2][0] += __popcll(a2 ^ b0); p[2][1] += __popcll(a2 ^ b1);
        p[2][2] += __popcll(a2 ^ b2); p[2][3] += __popcll(a2 ^ b3);
        p[3][0] += __popcll(a3 ^ b0); p[3][1] += __popcll(a3 ^ b1);
        p[3][2] += __popcll(a3 ^ b2); p[3][3] += __popcll(a3 ^ b3);
    }
    #pragma unroll
    for (int i = 0; i < 4; i++) {
        int d1 = t1 * 64 + g1 + 16 * i;
        #pragma unroll
        for (int j = 0; j < 4; j++) {
            int d2 = t2 * 64 + g2 + 16 * j;
            g_G[((size_t)(f * D_ + d1)) * D_ + d2] = (f16)(M_ - 2 * p[i][j]);
        }
    }
    if (t1 == t2) return;
    __syncthreads();
    f16* Lt = (f16*)L1T;
    #pragma unroll
    for (int i = 0; i < 4; i++)
        #pragma unroll
        for (int j = 0; j < 4; j++)
            Lt[(g2 + 16 * j) * 72 + (g1 + 16 * i)] = (f16)(M_ - 2 * p[i][j]);
    __syncthreads();
    int r = tid >> 2, c0 = (tid & 3) * 16;
    const uint4* s = (const uint4*)&Lt[r * 72 + c0];
    uint4 v0 = s[0], v1 = s[1];
    uint4* dsto = (uint4*)&g_G[((size_t)(f * D_ + t2 * 64 + r)) * D_ + t1 * 64 + c0];
    dsto[0] = v0; dsto[1] = v1;
}

__device__ __forceinline__ u32 pairval(u32 bits, int i) {
    // two bits -> two fp16: 0x3C00 (+1) / 0xBC00 (-1)
    return 0x3C003C00u | (((bits >> i) & 1u) << 15) | (((bits >> (i + 1)) & 1u) << 31);
}

// ---- fused 15-iter loop + cleanup; exclusive-line est exchange ----
// 64 blocks = f(4) x dg(16); block owns d-cols [dg*64, dg*64+64) = est word dg.
__global__ __launch_bounds__(256) void k_loop(float* __restrict__ out) {
    int blk = blockIdx.x;
    int f = blk & 3, dg = blk >> 2;
    int tid = threadIdx.x;
    int wv = tid >> 6, lane = tid & 63;
    __shared__ u64 neL[64][17];
    __shared__ u64 inL[64][17];
    __shared__ __align__(16) char ldsB[64 * 2048];  // 64 G-rows x 1024 k, XOR-swizzled
    __shared__ int red[256];
    {   // stage this block's G slice ONCE (128 KB)
        const char* gsrc = (const char*)(g_G + ((size_t)(f * D_ + dg * 64)) * D_);
        for (int i = tid; i < 8192; i += 256) {
            int row = i >> 7, col = i & 127;
            uint4 v = *(const uint4*)(gsrc + (size_t)row * 2048 + col * 16);
            *(uint4*)(ldsB + row * 2048 + ((col * 16) ^ ((row & 7) << 4))) = v;
        }
        for (int i = tid; i < 1024; i += 256)       // stage inBits ONCE
            inL[i >> 4][i & 15] = g_inBits[i];
    }
    const unsigned char* neB = (const unsigned char*)neL;
    int dd = lane & 15, gg = lane >> 4;
    int aBase = (wv * 16 + dd) * 136 + gg;
    int nb = tid & 63, wq = tid >> 6;               // ne task: batch nb, words wq*4..+3
    u64 prev[4];                                    // writer lanes' own est words
    if (dd == 0) {
        #pragma unroll
        for (int j = 0; j < 4; j++)
            prev[j] = g_est[0][(dg * 4 + f) * 64 + (wv * 16 + gg * 4 + j)];
    }
    for (int t = 0; t < NITER; t++) {
        const u64* rb = g_est[t & 1];
        u64* wb = g_est[(t + 1) & 1];
        {   // ne phase: 16 coalesced coherent loads, ONE waitcnt
            const char* base0 = (const char*)rb + (size_t)wq * 8192 + (size_t)nb * 8;
            const char* base1 = base0 + 4096;
            u64 e00, e01, e02, e03, e10, e11, e12, e13;
            u64 e20, e21, e22, e23, e30, e31, e32, e33;
            asm volatile(
                "global_load_dwordx2 %0, %16, off sc0 sc1\n\t"
                "global_load_dwordx2 %1, %16, off offset:512 sc0 sc1\n\t"
                "global_load_dwordx2 %2, %16, off offset:1024 sc0 sc1\n\t"
                "global_load_dwordx2 %3, %16, off offset:1536 sc0 sc1\n\t"
                "global_load_dwordx2 %4, %16, off offset:2048 sc0 sc1\n\t"
                "global_load_dwordx2 %5, %16, off offset:2560 sc0 sc1\n\t"
                "global_load_dwordx2 %6, %16, off offset:3072 sc0 sc1\n\t"
                "global_load_dwordx2 %7, %16, off offset:3584 sc0 sc1\n\t"
                "global_load_dwordx2 %8, %17, off sc0 sc1\n\t"
                "global_load_dwordx2 %9, %17, off offset:512 sc0 sc1\n\t"
                "global_load_dwordx2 %10, %17, off offset:1024 sc0 sc1\n\t"
                "global_load_dwordx2 %11, %17, off offset:1536 sc0 sc1\n\t"
                "global_load_dwordx2 %12, %17, off offset:2048 sc0 sc1\n\t"
                "global_load_dwordx2 %13, %17, off offset:2560 sc0 sc1\n\t"
                "global_load_dwordx2 %14, %17, off offset:3072 sc0 sc1\n\t"
                "global_load_dwordx2 %15, %17, off offset:3584 sc0 sc1\n\t"
                "s_waitcnt vmcnt(0)"
                : "=&v"(e00), "=&v"(e01), "=&v"(e02), "=&v"(e03),
                  "=&v"(e10), "=&v"(e11), "=&v"(e12), "=&v"(e13),
                  "=&v"(e20), "=&v"(e21), "=&v"(e22), "=&v"(e23),
                  "=&v"(e30), "=&v"(e31), "=&v"(e32), "=&v"(e33)
                : "v"(base0), "v"(base1)
                : "memory");
            // e{k}{f} = est[w=wq*4+k][f][nb]
            u64 x0 = inL[nb][wq * 4 + 0] ^ e00 ^ e01 ^ e02 ^ e03;
            u64 x1 = inL[nb][wq * 4 + 1] ^ e10 ^ e11 ^ e12 ^ e13;
            u64 x2 = inL[nb][wq * 4 + 2] ^ e20 ^ e21 ^ e22 ^ e23;
            u64 x3 = inL[nb][wq * 4 + 3] ^ e30 ^ e31 ^ e32 ^ e33;
            u64 f0 = (f == 0) ? e00 : (f == 1) ? e01 : (f == 2) ? e02 : e03;
            u64 f1 = (f == 0) ? e10 : (f == 1) ? e11 : (f == 2) ? e12 : e13;
            u64 f2 = (f == 0) ? e20 : (f == 1) ? e21 : (f == 2) ? e22 : e23;
            u64 f3 = (f == 0) ? e30 : (f == 1) ? e31 : (f == 2) ? e32 : e33;
            neL[nb][wq * 4 + 0] = x0 ^ f0;
            neL[nb][wq * 4 + 1] = x1 ^ f1;
            neL[nb][wq * 4 + 2] = x2 ^ f2;
            neL[nb][wq * 4 + 3] = x3 ^ f3;
        }
        __syncthreads();
        f32x4 acc[4][2] = {};
        #pragma unroll
        for (int c = 0; c < 32; c++) {
            u32 bits = neB[aBase + c * 4];
            f16x8 a;
            ((u32*)&a)[0] = pairval(bits, 0);
            ((u32*)&a)[1] = pairval(bits, 2);
            ((u32*)&a)[2] = pairval(bits, 4);
            ((u32*)&a)[3] = pairval(bits, 6);
            #pragma unroll
            for (int ct = 0; ct < 4; ct++) {
                int rowB = ct * 16 + dd;
                f16x8 bf = *(const f16x8*)(ldsB + rowB * 2048 +
                                           ((c * 64 + gg * 16) ^ ((rowB & 7) << 4)));
                acc[ct][c & 1] =
                    __builtin_amdgcn_mfma_f32_16x16x32_f16(a, bf, acc[ct][c & 1], 0, 0, 0);
            }
        }
        u64 msk[4][4];
        #pragma unroll
        for (int ct = 0; ct < 4; ct++)
            #pragma unroll
            for (int j = 0; j < 4; j++) {
                float v = acc[ct][0][j] + acc[ct][1][j];    // exact int
                msk[ct][j] = __ballot(v < 0.0f);
            }
        int mm = 0;
        if (dd == 0) {                              // writers: contiguous exclusive 512B
            #pragma unroll
            for (int j = 0; j < 4; j++) {
                int b = wv * 16 + gg * 4 + j;
                u64 nv = ((msk[0][j] >> (gg * 16)) & 0xFFFFu)
                       | (((msk[1][j] >> (gg * 16)) & 0xFFFFu) << 16)
                       | (((msk[2][j] >> (gg * 16)) & 0xFFFFu) << 32)
                       | (((msk[3][j] >> (gg * 16)) & 0xFFFFu) << 48);
                if (prev[j] != nv) mm = 1;
                prev[j] = nv;
                ST_AG(&wb[(dg * 4 + f) * 64 + b], nv);
            }
        }
        u64 anym = __ballot(mm != 0);
        if (lane == 0 && anym)
            ST_AG(&g_mism[t][blk * FPAD + wv], 1);  // own line, no RMW
        __syncthreads();                            // vmcnt(0) drain of ALL waves' stores
        if (tid == 0)
            ST_AG(&g_done[t][blk * FPAD], 1);
        if (tid < NBLK) {                           // each thread polls one distinct line
            while (LD_AG(&g_done[t][tid * FPAD]) == 0) {}
        }
        __syncthreads();
    }
    // ---- iters/conv from mismatch history (monotone c_t) ----
    const u64* eb_g = g_est[NITER & 1];
    if (blk == 0 && tid < NBLK) {
        int anyt[NITER];
        #pragma unroll
        for (int t = 0; t < NITER; t++) {
            const int* mp = &g_mism[t][tid * FPAD];
            int v = LD_AG(&mp[0]) | LD_AG(&mp[1]) | LD_AG(&mp[2]) | LD_AG(&mp[3]);
            anyt[t] = (__ballot(v != 0) != 0);
        }
        if (tid == 0) {
            int iters = 0, conv = 0;
            #pragma unroll
            for (int t = 0; t < NITER; t++) {
                if (!conv) iters++;
                if (!anyt[t]) conv = 1;
            }
            out[256 + 262144] = (float)iters;
            out[256 + 262144 + 1] = (float)conv;
        }
    }
    // ---- final cleanup: 4 (b,f) tasks per block ----
    for (int s = 0; s < 4; s++) {
        int task = blk * 4 + s;
        int bb = task >> 2, ff = task & 3;
        for (int j = 0; j < 4; j++) {
            int d = j * 256 + tid;
            u64 w = LD_AG(&eb_g[((d >> 6) * 4 + ff) * 64 + bb]);
            out[256 + ((size_t)(bb * 4 + ff)) * D_ + d] = ((w >> (d & 63)) & 1) ? -1.0f : 1.0f;
        }
        u64 eb[W_];
        #pragma unroll
        for (int w = 0; w < W_; w++) eb[w] = LD_AG(&eb_g[(w * 4 + ff) * 64 + bb]);
        int bestKey = -1;
        for (int j = 0; j < 16; j++) {
            int m = j * 256 + tid;
            int p = 0;
            #pragma unroll
            for (int w = 0; w < W_; w++)
                p += __popcll(eb[w] ^ g_cbBits[((size_t)(ff * M_ + m)) * W_ + w]);
            int sv = D_ - 2 * p;
            int a = sv < 0 ? -sv : sv;
            int key = (a << 12) | (4095 - m);   // max |sim|, then min m
            if (key > bestKey) bestKey = key;
        }
        red[tid] = bestKey;
        __syncthreads();
        for (int off = 128; off > 0; off >>= 1) {
            if (tid < off) red[tid] = max(red[tid], red[tid + off]);
            __syncthreads();
        }
        if (tid == 0) out[bb * 4 + ff] = (float)(4095 - (red[0] & 0xFFF));
        __syncthreads();
    }
}

extern "C" void kernel_launch(void* const* d_in, const int* in_sizes, int n_in,
                              void* d_out, int out_size, void* d_ws, size_t ws_size,
                              hipStream_t stream) {
    (void)d_ws; (void)ws_size;
    const float* inp  = (const float*)d_in[0];
    const float* est0 = (const float*)d_in[1];
    const float* cb   = (const float*)d_in[2];
    float* out = (float*)d_out;

    int flagInts = 2 * NITER * NBLK * FPAD;
    int zeroBlks = (flagInts + 255) / 256;          // 240
    k_pack<<<1044 + zeroBlks, 256, 0, stream>>>(inp, est0, cb);
    k_bitT<<<256, 256, 0, stream>>>();
    k_G<<<544, 256, 0, stream>>>();
    k_loop<<<NBLK, 256, 0, stream>>>(out);
}

// Round 12
// 296.095 us; speedup vs baseline: 1.0247x; 1.0247x over previous
//
#include <hip/hip_runtime.h>
#include <hip/hip_fp16.h>

#define B_ 64
#define F_ 4
#define M_ 4096
#define D_ 1024
#define W_ 16      // u64 words per D bits
#define CW_ 64     // u64 words per M bits
#define NITER 15
#define NSLOT 16   // est slots: 0 = initial, t+1 written at end of iter t
#define NBLK 64    // loop blocks: f(4) x dg(16)
#define FPAD 16    // ints per flag line (64B)

typedef _Float16 f16;
typedef _Float16 f16x8 __attribute__((ext_vector_type(8)));
typedef float f32x4 __attribute__((ext_vector_type(4)));
typedef unsigned int u32;
typedef unsigned short u16;
typedef unsigned long long u64;

#define LD_AG(p)     __hip_atomic_load((p), __ATOMIC_RELAXED, __HIP_MEMORY_SCOPE_AGENT)
#define ST_AG(p, v)  __hip_atomic_store((p), (v), __ATOMIC_RELAXED, __HIP_MEMORY_SCOPE_AGENT)

// ---- device-global scratch (rebuilt every call) ----
__device__ __align__(16) u64 g_cbBits[F_ * M_ * W_];    // 2 MB: cb packed along d
__device__ __align__(16) u64 g_colBits[F_ * D_ * CW_];  // 2 MB: cb packed along m
__device__ __align__(16) f16 g_G[F_ * D_ * D_];         // 8 MB: G = cb^T cb (exact fp16 ints)
__device__ __align__(16) u64 g_inBits[B_ * W_];
// est slots: [slot][producer p=f*16+w][b]  (each producer's 512B is write-once/exclusive)
__device__ __align__(16) u64 g_ex[NSLOT][64][64];
__device__ int g_fl[NSLOT][64 * FPAD];                  // slot-ready flags, 1 line/producer
__device__ int g_mism[NITER][NBLK * FPAD];              // mismatch flags, 1 line/block

__device__ __forceinline__ u32 nib16(u32 x) {
    x &= 0x0F0F0F0Fu;
    x = (x | (x >> 4)) & 0x00FF00FFu;
    x = (x | (x >> 8)) & 0x0000FFFFu;
    return x;
}

// ---- bit-pack via nibble-LDS + zero flag arrays ----
__global__ __launch_bounds__(256) void k_pack(const float* __restrict__ inp,
                                              const float* __restrict__ est0,
                                              const float* __restrict__ cb) {
    __shared__ unsigned char nib[4096];   // 4 waves x 4 rows x 256 nibbles
    int blk = blockIdx.x, tid = threadIdx.x;
    int wv = tid >> 6, lane = tid & 63;
    const float* src; int r0; int mode;   // 0=cb 1=est0 2=inp
    if (blk < 1024)      { src = cb;   r0 = blk * 16;          mode = 0; }
    else if (blk < 1040) { src = est0; r0 = (blk - 1024) * 16; mode = 1; }
    else if (blk < 1044) { src = inp;  r0 = (blk - 1040) * 16; mode = 2; }
    else {                                 // zero g_fl + g_mism
        int idx = (blk - 1044) * 256 + tid;
        const int n1 = NSLOT * 64 * FPAD;
        const int n2 = NITER * NBLK * FPAD;
        if (idx < n1) ((int*)g_fl)[idx] = 0;
        else if (idx < n1 + n2) ((int*)g_mism)[idx - n1] = 0;
        return;
    }
    int rw = r0 + wv * 4;
    unsigned char* mynib = nib + wv * 1024;
    #pragma unroll
    for (int rr = 0; rr < 4; rr++) {
        const float4* s4 = (const float4*)(src + (size_t)(rw + rr) * D_);
        #pragma unroll
        for (int it = 0; it < 4; it++) {
            float4 v = s4[it * 64 + lane];
            u32 n = (__float_as_uint(v.x) >> 31)
                  | (((__float_as_uint(v.y) >> 31)) << 1)
                  | (((__float_as_uint(v.z) >> 31)) << 2)
                  | (((__float_as_uint(v.w) >> 31)) << 3);
            mynib[rr * 256 + it * 64 + lane] = (unsigned char)n;
        }
    }
    uint4 q = *(const uint4*)(mynib + (lane >> 4) * 256 + (lane & 15) * 16);
    u32 w0 = nib16(q.x), w1 = nib16(q.y), w2 = nib16(q.z), w3 = nib16(q.w);
    u64 word = (u64)(w0 | (w1 << 16)) | ((u64)(w2 | (w3 << 16)) << 32);
    int r = rw + (lane >> 4), w = lane & 15;
    if (mode == 0)      g_cbBits[(size_t)r * W_ + w] = word;
    else if (mode == 2) g_inBits[r * W_ + w] = word;
    else {              // est0 -> slot 0: r = b*4+f
        int b = r >> 2, ff = r & 3;
        g_ex[0][ff * 16 + w][b] = word;
    }
}

// ---- 64x64 bit-transpose: cbBits[m][wd] -> colBits[d][wm] ----
__global__ __launch_bounds__(256) void k_bitT() {
    int tid = threadIdx.x, wv = tid >> 6, lane = tid & 63;
    int tbase = (blockIdx.x * 4 + wv) * 4;
    for (int q = 0; q < 4; q++) {
        int task = tbase + q;
        int mt = task & 63;
        int wd = (task >> 6) & 15;
        int f  = task >> 10;
        u64 row = g_cbBits[((size_t)(f * M_ + mt * 64 + lane)) * W_ + wd];
        u64 myout = 0;
        #pragma unroll
        for (int j = 0; j < 64; j++) {
            u64 t = __ballot((row >> j) & 1ULL);
            if (lane == j) myout = t;
        }
        g_colBits[((size_t)(f * D_ + wd * 64 + lane)) * CW_ + mt] = myout;
    }
}

// ---- G = cb^T cb, symmetric pairs; w-split tiles (32KB LDS -> ~5 blocks/CU) ----
__global__ __launch_bounds__(256) void k_G() {
    int blk = blockIdx.x;                  // 544 = f(4) x 136 pairs
    int f = blk / 136;
    int pi = blk % 136;
    int t1 = 0;
    while (pi >= 16 - t1) { pi -= 16 - t1; t1++; }
    int t2 = t1 + pi;
    __shared__ u64 L1T[32][64];            // [w-half][d_loc]
    __shared__ u64 L2T[32][64];
    int tid = threadIdx.x;
    int wv = tid >> 6, lane = tid & 63;
    int g1 = tid >> 4, g2 = tid & 15;
    int p[4][4] = {};
    for (int wh = 0; wh < 2; wh++) {
        for (int it = 0; it < 8; it++) {
            int w = it * 4 + wv;
            L1T[w][lane] = g_colBits[((size_t)(f * D_ + t1 * 64 + lane)) * CW_ + wh * 32 + w];
            L2T[w][lane] = g_colBits[((size_t)(f * D_ + t2 * 64 + lane)) * CW_ + wh * 32 + w];
        }
        __syncthreads();
        for (int w = 0; w < 32; w++) {
            u64 a0 = L1T[w][g1], a1 = L1T[w][g1 + 16], a2 = L1T[w][g1 + 32], a3 = L1T[w][g1 + 48];
            u64 b0 = L2T[w][g2], b1 = L2T[w][g2 + 16], b2 = L2T[w][g2 + 32], b3 = L2T[w][g2 + 48];
            p[0][0] += __popcll(a0 ^ b0); p[0][1] += __popcll(a0 ^ b1);
            p[0][2] += __popcll(a0 ^ b2); p[0][3] += __popcll(a0 ^ b3);
            p[1][0] += __popcll(a1 ^ b0); p[1][1] += __popcll(a1 ^ b1);
            p[1][2] += __popcll(a1 ^ b2); p[1][3] += __popcll(a1 ^ b3);
            p[2][0] += __popcll(a2 ^ b0); p[2][1] += __popcll(a2 ^ b1);
            p[2][2] += __popcll(a2 ^ b2); p[2][3] += __popcll(a2 ^ b3);
            p[3][0] += __popcll(a3 ^ b0); p[3][1] += __popcll(a3 ^ b1);
            p[3][2] += __popcll(a3 ^ b2); p[3][3] += __popcll(a3 ^ b3);
        }
        __syncthreads();
    }
    #pragma unroll
    for (int i = 0; i < 4; i++) {
        int d1 = t1 * 64 + g1 + 16 * i;
        #pragma unroll
        for (int j = 0; j < 4; j++) {
            int d2 = t2 * 64 + g2 + 16 * j;
            g_G[((size_t)(f * D_ + d1)) * D_ + d2] = (f16)(M_ - 2 * p[i][j]);
        }
    }
    if (t1 == t2) return;
    __syncthreads();
    f16* Lt = (f16*)L1T;                   // 64x72 f16 = 9KB fits L1T region
    #pragma unroll
    for (int i = 0; i < 4; i++)
        #pragma unroll
        for (int j = 0; j < 4; j++)
            Lt[(g2 + 16 * j) * 72 + (g1 + 16 * i)] = (f16)(M_ - 2 * p[i][j]);
    __syncthreads();
    int r = tid >> 2, c0 = (tid & 3) * 16;
    const uint4* s = (const uint4*)&Lt[r * 72 + c0];
    uint4 v0 = s[0], v1 = s[1];
    uint4* dsto = (uint4*)&g_G[((size_t)(f * D_ + t2 * 64 + r)) * D_ + t1 * 64 + c0];
    dsto[0] = v0; dsto[1] = v1;
}

__device__ __forceinline__ u32 pairval(u32 bits, int i) {
    // two bits -> two fp16: 0x3C00 (+1) / 0xBC00 (-1)
    return 0x3C003C00u | (((bits >> i) & 1u) << 15) | (((bits >> (i + 1)) & 1u) << 31);
}

// ---- fused 15-iter loop; per-producer flags + eager gather (overlap transfer/wait) ----
// 64 blocks = f(4) x dg(16); producer p=f*16+dg writes word dg of est[b][f] for all b.
// ne = in ^ XOR_{f'!=f} est[f'] (own factor cancels: e^e=1) -> gather only 48 producers.
__global__ __launch_bounds__(256) void k_loop(float* __restrict__ out) {
    int blk = blockIdx.x;
    int f = blk & 3, dg = blk >> 2;
    int tid = threadIdx.x;
    int wv = tid >> 6, lane = tid & 63;
    __shared__ u64 neL[64][17];
    __shared__ u64 inL[64][16];
    __shared__ __align__(16) char ldsB[64 * 2048];  // 64 G-rows x 1024 k, XOR-swizzled
    __shared__ int red[256];
    {   // stage G slice + inBits ONCE
        const char* gsrc = (const char*)(g_G + ((size_t)(f * D_ + dg * 64)) * D_);
        for (int i = tid; i < 8192; i += 256) {
            int row = i >> 7, col = i & 127;
            uint4 v = *(const uint4*)(gsrc + (size_t)row * 2048 + col * 16);
            *(uint4*)(ldsB + row * 2048 + ((col * 16) ^ ((row & 7) << 4))) = v;
        }
        for (int i = tid; i < 1024; i += 256)
            inL[i >> 4][i & 15] = g_inBits[i];
    }
    const unsigned char* neB = (const unsigned char*)neL;
    unsigned long long* nf = (unsigned long long*)neL;
    int dd = lane & 15, gg = lane >> 4;
    int aBase = (wv * 16 + dd) * 136 + gg;
    int myp = f * 16 + dg;
    // gather assignment (tid<192): producer q among the 48 with f'!=f, word chunk sub
    int q = tid >> 2, sub = tid & 3;
    int fp = q >> 4; if (fp >= f) fp++;
    int gp = fp * 16 + (q & 15);                    // global producer id
    u64 prev[4];                                    // writer lanes' own est words
    if (dd == 0) {
        #pragma unroll
        for (int j = 0; j < 4; j++)
            prev[j] = LD_AG(&g_ex[0][myp][wv * 16 + gg * 4 + j]);
    }
    __syncthreads();
    for (int t = 0; t < NITER; t++) {
        {   // init ne = in
            int c0 = tid * 4;
            #pragma unroll
            for (int k = 0; k < 4; k++) {
                int c = c0 + k;
                neL[c >> 4][c & 15] = inL[c >> 4][c & 15];
            }
        }
        __syncthreads();
        if (tid < 192) {                            // eager gather: poll own producer, pull, xor
            if (t) { while (LD_AG(&g_fl[t][gp * FPAD]) == 0) {} }
            const char* bb = (const char*)&g_ex[t][gp][sub * 16];
            uint4 r0, r1, r2, r3, r4, r5, r6, r7;
            asm volatile(
                "global_load_dwordx4 %0, %8, off sc0 sc1\n\t"
                "global_load_dwordx4 %1, %8, off offset:16 sc0 sc1\n\t"
                "global_load_dwordx4 %2, %8, off offset:32 sc0 sc1\n\t"
                "global_load_dwordx4 %3, %8, off offset:48 sc0 sc1\n\t"
                "global_load_dwordx4 %4, %8, off offset:64 sc0 sc1\n\t"
                "global_load_dwordx4 %5, %8, off offset:80 sc0 sc1\n\t"
                "global_load_dwordx4 %6, %8, off offset:96 sc0 sc1\n\t"
                "global_load_dwordx4 %7, %8, off offset:112 sc0 sc1\n\t"
                "s_waitcnt vmcnt(0)"
                : "=&v"(r0), "=&v"(r1), "=&v"(r2), "=&v"(r3),
                  "=&v"(r4), "=&v"(r5), "=&v"(r6), "=&v"(r7)
                : "v"(bb)
                : "memory");
            int wp = gp & 15;
            int bb0 = sub * 16;
            u64 d[16];
            d[0]=r0.x|((u64)r0.y<<32); d[1]=r0.z|((u64)r0.w<<32);
            d[2]=r1.x|((u64)r1.y<<32); d[3]=r1.z|((u64)r1.w<<32);
            d[4]=r2.x|((u64)r2.y<<32); d[5]=r2.z|((u64)r2.w<<32);
            d[6]=r3.x|((u64)r3.y<<32); d[7]=r3.z|((u64)r3.w<<32);
            d[8]=r4.x|((u64)r4.y<<32); d[9]=r4.z|((u64)r4.w<<32);
            d[10]=r5.x|((u64)r5.y<<32); d[11]=r5.z|((u64)r5.w<<32);
            d[12]=r6.x|((u64)r6.y<<32); d[13]=r6.z|((u64)r6.w<<32);
            d[14]=r7.x|((u64)r7.y<<32); d[15]=r7.z|((u64)r7.w<<32);
            #pragma unroll
            for (int k = 0; k < 16; k++)
                atomicXor(&nf[(bb0 + k) * 17 + wp], d[k]);
        }
        __syncthreads();                            // all xors done -> neL complete
        f32x4 acc[4][2] = {};
        #pragma unroll
        for (int c = 0; c < 32; c++) {
            u32 bits = neB[aBase + c * 4];
            f16x8 a;
            ((u32*)&a)[0] = pairval(bits, 0);
            ((u32*)&a)[1] = pairval(bits, 2);
            ((u32*)&a)[2] = pairval(bits, 4);
            ((u32*)&a)[3] = pairval(bits, 6);
            #pragma unroll
            for (int ct = 0; ct < 4; ct++) {
                int rowB = ct * 16 + dd;
                f16x8 bf = *(const f16x8*)(ldsB + rowB * 2048 +
                                           ((c * 64 + gg * 16) ^ ((rowB & 7) << 4)));
                acc[ct][c & 1] =
                    __builtin_amdgcn_mfma_f32_16x16x32_f16(a, bf, acc[ct][c & 1], 0, 0, 0);
            }
        }
        u64 msk[4][4];
        #pragma unroll
        for (int ct = 0; ct < 4; ct++)
            #pragma unroll
            for (int j = 0; j < 4; j++) {
                float v = acc[ct][0][j] + acc[ct][1][j];    // exact int
                msk[ct][j] = __ballot(v < 0.0f);
            }
        int mm = 0;
        if (dd == 0) {                              // writers: exclusive 512B slot region
            #pragma unroll
            for (int j = 0; j < 4; j++) {
                int b = wv * 16 + gg * 4 + j;
                u64 nv = ((msk[0][j] >> (gg * 16)) & 0xFFFFu)
                       | (((msk[1][j] >> (gg * 16)) & 0xFFFFu) << 16)
                       | (((msk[2][j] >> (gg * 16)) & 0xFFFFu) << 32)
                       | (((msk[3][j] >> (gg * 16)) & 0xFFFFu) << 48);
                if (prev[j] != nv) mm = 1;
                prev[j] = nv;
                ST_AG(&g_ex[t + 1][myp][b], nv);
            }
        }
        u64 anym = __ballot(mm != 0);
        if (lane == 0 && anym)
            ST_AG(&g_mism[t][blk * FPAD + wv], 1);  // own line, no RMW
        __syncthreads();                            // vmcnt(0): all est stores at L3
        if (tid == 0)
            ST_AG(&g_fl[t + 1][myp * FPAD], 1);     // slot t+1 ready (this producer)
    }
    // ---- wait for all slot-15 producers, then cleanup ----
    if (tid < 64) { while (LD_AG(&g_fl[NITER][tid * FPAD]) == 0) {} }
    __syncthreads();
    if (blk == 0 && tid < NBLK) {                   // iters/conv from mism history
        int anyt[NITER];
        #pragma unroll
        for (int t = 0; t < NITER; t++) {
            const int* mp = &g_mism[t][tid * FPAD];
            int v = LD_AG(&mp[0]) | LD_AG(&mp[1]) | LD_AG(&mp[2]) | LD_AG(&mp[3]);
            anyt[t] = (__ballot(v != 0) != 0);
        }
        if (tid == 0) {
            int iters = 0, conv = 0;
            #pragma unroll
            for (int t = 0; t < NITER; t++) {
                if (!conv) iters++;
                if (!anyt[t]) conv = 1;
            }
            out[256 + 262144] = (float)iters;
            out[256 + 262144 + 1] = (float)conv;
        }
    }
    for (int s = 0; s < 4; s++) {                   // 4 (b,f) tasks per block
        int task = blk * 4 + s;
        int bb = task >> 2, ff = task & 3;
        for (int j = 0; j < 4; j++) {
            int d = j * 256 + tid;
            u64 w = LD_AG(&g_ex[NITER][ff * 16 + (d >> 6)][bb]);
            out[256 + ((size_t)(bb * 4 + ff)) * D_ + d] = ((w >> (d & 63)) & 1) ? -1.0f : 1.0f;
        }
        u64 eb[W_];
        #pragma unroll
        for (int w = 0; w < W_; w++) eb[w] = LD_AG(&g_ex[NITER][ff * 16 + w][bb]);
        int bestKey = -1;
        for (int j = 0; j < 16; j++) {
            int m = j * 256 + tid;
            int p = 0;
            #pragma unroll
            for (int w = 0; w < W_; w++)
                p += __popcll(eb[w] ^ g_cbBits[((size_t)(ff * M_ + m)) * W_ + w]);
            int sv = D_ - 2 * p;
            int a = sv < 0 ? -sv : sv;
            int key = (a << 12) | (4095 - m);   // max |sim|, then min m
            if (key > bestKey) bestKey = key;
        }
        red[tid] = bestKey;
        __syncthreads();
        for (int off = 128; off > 0; off >>= 1) {
            if (tid < off) red[tid] = max(red[tid], red[tid + off]);
            __syncthreads();
        }
        if (tid == 0) out[bb * 4 + ff] = (float)(4095 - (red[0] & 0xFFF));
        __syncthreads();
    }
}

extern "C" void kernel_launch(void* const* d_in, const int* in_sizes, int n_in,
                              void* d_out, int out_size, void* d_ws, size_t ws_size,
                              hipStream_t stream) {
    (void)d_ws; (void)ws_size;
    const float* inp  = (const float*)d_in[0];
    const float* est0 = (const float*)d_in[1];
    const float* cb   = (const float*)d_in[2];
    float* out = (float*)d_out;

    int flagInts = NSLOT * 64 * FPAD + NITER * NBLK * FPAD;
    int zeroBlks = (flagInts + 255) / 256;
    k_pack<<<1044 + zeroBlks, 256, 0, stream>>>(inp, est0, cb);
    k_bitT<<<256, 256, 0, stream>>>();
    k_G<<<544, 256, 0, stream>>>();
    k_loop<<<NBLK, 256, 0, stream>>>(out);
}